// Round 6
// baseline (350.252 us; speedup 1.0000x reference)
//
#include <hip/hip_runtime.h>

#define S_LEN 2048
#define BATCH 16
#define DIM   512
#define KVB   64
#define NT    (S_LEN / KVB)   // 32

typedef __bf16 bf16x8 __attribute__((ext_vector_type(8)));
typedef float  f32x4  __attribute__((ext_vector_type(4)));
typedef float  f32x16 __attribute__((ext_vector_type(16)));
typedef unsigned int u32x4 __attribute__((ext_vector_type(4)));

static __device__ __forceinline__ unsigned short f2bf(float f) {
    __bf16 h = (__bf16)f;
    return __builtin_bit_cast(unsigned short, h);
}
static __device__ __forceinline__ bf16x8 ld_bf8(const unsigned short* p) {
    u32x4 v = *reinterpret_cast<const u32x4*>(p);
    return __builtin_bit_cast(bf16x8, v);
}
static __device__ __forceinline__ f32x4 mfma16(bf16x8 a, bf16x8 b, f32x4 c) {
    return __builtin_amdgcn_mfma_f32_16x16x32_bf16(a, b, c, 0, 0, 0);
}
static __device__ __forceinline__ f32x16 mfma32(bf16x8 a, bf16x8 b, f32x16 c) {
    return __builtin_amdgcn_mfma_f32_32x32x16_bf16(a, b, c, 0, 0, 0);
}
static __device__ __forceinline__ void gload16(const unsigned short* g, unsigned short* l) {
    __builtin_amdgcn_global_load_lds(
        (const __attribute__((address_space(1))) unsigned int*)g,
        (__attribute__((address_space(3))) unsigned int*)l, 16, 0, 0);
}
#define WAITV(N) do { asm volatile("s_waitcnt vmcnt(" #N ")" ::: "memory"); \
                      __builtin_amdgcn_sched_barrier(0); } while (0)
static __device__ __forceinline__ void waitlg0() {
    asm volatile("s_waitcnt lgkmcnt(0)" ::: "memory");
    __builtin_amdgcn_sched_barrier(0);
}

// ---------------- pack V^T: seq [S][B][D] f32 -> vt [B][D][S] bf16 ----------------
__global__ void pack_vt(const float* __restrict__ seq, unsigned short* __restrict__ vt) {
    __shared__ float tile[32][33];
    int b  = blockIdx.z;
    int d0 = blockIdx.y * 32;
    int s0 = blockIdx.x * 32;
    int t  = threadIdx.x;
    {
        int sl = t >> 3, c4 = (t & 7) * 4;
        float4 v = *reinterpret_cast<const float4*>(
            seq + (size_t)(s0 + sl) * (BATCH * DIM) + (size_t)b * DIM + d0 + c4);
        tile[sl][c4 + 0] = v.x; tile[sl][c4 + 1] = v.y;
        tile[sl][c4 + 2] = v.z; tile[sl][c4 + 3] = v.w;
    }
    __syncthreads();
    {
        int dl = t >> 3, s4 = (t & 7) * 4;
        uint2 r;
        r.x = (unsigned)f2bf(tile[s4 + 0][dl]) | ((unsigned)f2bf(tile[s4 + 1][dl]) << 16);
        r.y = (unsigned)f2bf(tile[s4 + 2][dl]) | ((unsigned)f2bf(tile[s4 + 3][dl]) << 16);
        *reinterpret_cast<uint2*>(
            vt + (size_t)b * DIM * S_LEN + (size_t)(d0 + dl) * S_LEN + s0 + s4) = r;
    }
}

// -------- value = tanh(seq_in @ Wv^T + bv) -> bf16 [B*S][512], Wv f32 inline --------
__global__ void __launch_bounds__(256) gemm_value(
        const float* __restrict__ seq, const float* __restrict__ wv,
        const float* __restrict__ bv, unsigned short* __restrict__ val) {
    __shared__ unsigned short Asm[64][72];
    __shared__ unsigned short Bsm[64][72];
    int t  = threadIdx.x;
    int rb = blockIdx.x * 64;
    int cb = blockIdx.y * 64;
    int w = t >> 6, l = t & 63;
    int mi = w >> 1, ni = w & 1;
    int l15 = l & 15, lh = l >> 4;
    f32x4 acc[2][2] = {};

    int srow = t >> 2;
    int qc   = (t & 3) * 16;
    int gr = rb + srow;
    int sb = gr >> 11, ss = gr & 2047;
    const float* aSrc = seq + ((size_t)ss * BATCH + sb) * DIM + qc;
    const float* bSrc = wv + (size_t)(cb + srow) * DIM + qc;

    for (int k0 = 0; k0 < DIM; k0 += 64) {
        unsigned short ar[16], br[16];
        #pragma unroll
        for (int j = 0; j < 4; ++j) {
            float4 v = *reinterpret_cast<const float4*>(aSrc + k0 + j * 4);
            ar[j * 4 + 0] = f2bf(v.x); ar[j * 4 + 1] = f2bf(v.y);
            ar[j * 4 + 2] = f2bf(v.z); ar[j * 4 + 3] = f2bf(v.w);
            float4 u = *reinterpret_cast<const float4*>(bSrc + k0 + j * 4);
            br[j * 4 + 0] = f2bf(u.x); br[j * 4 + 1] = f2bf(u.y);
            br[j * 4 + 2] = f2bf(u.z); br[j * 4 + 3] = f2bf(u.w);
        }
        *reinterpret_cast<u32x4*>(&Asm[srow][qc])     = *reinterpret_cast<u32x4*>(&ar[0]);
        *reinterpret_cast<u32x4*>(&Asm[srow][qc + 8]) = *reinterpret_cast<u32x4*>(&ar[8]);
        *reinterpret_cast<u32x4*>(&Bsm[srow][qc])     = *reinterpret_cast<u32x4*>(&br[0]);
        *reinterpret_cast<u32x4*>(&Bsm[srow][qc + 8]) = *reinterpret_cast<u32x4*>(&br[8]);
        __syncthreads();
        #pragma unroll
        for (int kf = 0; kf < 2; ++kf) {
            bf16x8 af[2], bfm[2];
            #pragma unroll
            for (int i = 0; i < 2; ++i)
                af[i] = ld_bf8(&Asm[mi * 32 + i * 16 + l15][kf * 32 + lh * 8]);
            #pragma unroll
            for (int j = 0; j < 2; ++j)
                bfm[j] = ld_bf8(&Bsm[ni * 32 + j * 16 + l15][kf * 32 + lh * 8]);
            #pragma unroll
            for (int i = 0; i < 2; ++i)
                #pragma unroll
                for (int j = 0; j < 2; ++j)
                    acc[i][j] = mfma16(af[i], bfm[j], acc[i][j]);
        }
        __syncthreads();
    }
    #pragma unroll
    for (int i = 0; i < 2; ++i) {
        #pragma unroll
        for (int j = 0; j < 2; ++j) {
            int gcol = cb + ni * 32 + j * 16 + l15;
            float bias = bv[gcol];
            #pragma unroll
            for (int r = 0; r < 4; ++r) {
                int grow = rb + mi * 32 + i * 16 + lh * 4 + r;
                float x = acc[i][j][r] + bias;
                val[(size_t)grow * DIM + gcol] = f2bf(tanhf(x));
            }
        }
    }
}

// ---------------- fused flash attention v6 ----------------
// QB=64, KVB=64, 8 waves, 3 barriers/iter. K: reg-staged double buffer
// (regs idle at 2 waves/SIMD anyway); V: single-buffered via global_load_lds.
// Counted vmcnt pipeline: issue order per iter = [K(kt+2)@C, V(kt)@A];
// B: vmcnt(8) retires K(kt+1); C: vmcnt(0) retires V(kt). Defer-max THR=8.
__global__ void __launch_bounds__(512, 2) attn_fused(
        const unsigned short* __restrict__ val, const unsigned short* __restrict__ vt,
        float* __restrict__ out) {
    extern __shared__ char smem[];
    unsigned short* Kt = (unsigned short*)smem;              // [64][512]  64KB swz
    unsigned short* Vt = (unsigned short*)(smem + 65536);    // [512][64]  64KB swz
    float*          Sb = (float*)(smem + 131072);            // [64][68]   17408B
    unsigned short* Pb = (unsigned short*)(smem + 148480);   // [64][72]   9216B
    float* stm = (float*)(smem + 157696);                    // [64]
    float* stl = stm + 64;
    float* sts = stm + 128;

    const int t = threadIdx.x;
    const int w = t >> 6, l = t & 63;
    const int l15 = l & 15, lh = l >> 4;
    const int l31 = l & 31, lh1 = l >> 5;

    int wg  = blockIdx.x;
    int swz = (wg & 7) * 64 + (wg >> 3);     // XCD-chunked, bijective (512 = 8*64)
    int b   = swz >> 5;
    int qb  = (swz & 31) * 64;

    const int qi = w & 3, khi = w >> 2;      // QK: S[qi*16..+16][khi*32..+32]
    const int qi2 = w & 1, dq = w >> 1;      // PV: O[qi2*32..+32][dq*128..+128]

    const unsigned short* valb = val + (size_t)b * S_LEN * DIM;
    const unsigned short* vtb  = vt  + (size_t)b * DIM * S_LEN;

    if (t < 64) { stm[t] = -3.0e38f; stl[t] = 0.0f; }

    // Q fragments: rows qb + qi*16 + l15, full K=512 (64 VGPR)
    bf16x8 qf[16];
    {
        const unsigned short* qrow = valb + (size_t)(qb + qi * 16 + l15) * DIM + lh * 8;
        #pragma unroll
        for (int kf = 0; kf < 16; ++kf) qf[kf] = ld_bf8(qrow + kf * 32);
    }
    f32x16 o[4] = {};   // 32q x 128d

    // ---- K reg-staging: thread -> (row = t>>3, granules g = (t&7)+8j) ----
    u32x4 kreg[8];
    const int krow = t >> 3, kseg = t & 7;
    auto loadK = [&](int tile) {
        const unsigned short* src = valb + (size_t)(tile * KVB + krow) * DIM + kseg * 8;
        #pragma unroll
        for (int j = 0; j < 8; ++j)
            kreg[j] = *reinterpret_cast<const u32x4*>(src + j * 64);
    };
    auto writeK = [&]() {
        unsigned short* dst = Kt + krow * 512;
        #pragma unroll
        for (int j = 0; j < 8; ++j)
            *reinterpret_cast<u32x4*>(dst + (((kseg + j * 8) ^ (krow & 7)) * 8)) = kreg[j];
    };
    // ---- V staging: global_load_lds, linear dest, pre-swizzled source ----
    auto issueV = [&](int tile) {
        int kv0 = tile * KVB;
        #pragma unroll
        for (int i = 0; i < 8; ++i) {
            int d = w * 64 + i * 8 + (l >> 3);
            gload16(vtb + (size_t)d * S_LEN + kv0 + (((l & 7) ^ (d & 7)) * 8),
                    Vt + (w * 64 + i * 8) * 64);
        }
    };
    auto qk_compute = [&](int tile) {
        const unsigned short* kb0 = Kt + (khi * 32 + l15) * 512;
        const unsigned short* kb1 = kb0 + 16 * 512;
        const int rx8 = (l15 & 7) << 3;                 // swizzle XOR (shorts)
        f32x4 a00 = {}, a01 = {}, a10 = {}, a11 = {};
        __builtin_amdgcn_s_setprio(1);
        #pragma unroll
        for (int kf = 0; kf < 16; kf += 2) {
            int o0 = (kf * 32 + lh * 8) ^ rx8;
            int o1 = ((kf + 1) * 32 + lh * 8) ^ rx8;
            bf16x8 k00 = ld_bf8(kb0 + o0);
            bf16x8 k10 = ld_bf8(kb1 + o0);
            bf16x8 k01 = ld_bf8(kb0 + o1);
            bf16x8 k11 = ld_bf8(kb1 + o1);
            a00 = mfma16(qf[kf], k00, a00);
            a10 = mfma16(qf[kf], k10, a10);
            a01 = mfma16(qf[kf + 1], k01, a01);
            a11 = mfma16(qf[kf + 1], k11, a11);
        }
        __builtin_amdgcn_s_setprio(0);
        f32x4 s0 = a00 + a01, s1 = a10 + a11;
        #pragma unroll
        for (int r = 0; r < 4; ++r) {
            Sb[(qi * 16 + lh * 4 + r) * 68 + khi * 32 + l15]      = s0[r];
            Sb[(qi * 16 + lh * 4 + r) * 68 + khi * 32 + 16 + l15] = s1[r];
        }
    };

    // ---- prologue: K(0) -> LDS, K(1) -> regs ----
    loadK(0);
    WAITV(0);
    writeK();
    loadK(1);
    waitlg0();
    __builtin_amdgcn_s_barrier();

    for (int kt = 0; kt < NT; ++kt) {
        // ---- phase A: issue V(kt); QK(kt) ----
        issueV(kt);
        qk_compute(kt);
        waitlg0();
        __builtin_amdgcn_s_barrier();

        // ---- phase B: retire K(kt+1) regs; write K; softmax(kt) ----
        WAITV(8);
        writeK();
        {
            int row = t >> 3, e = t & 7;
            const float* sp = Sb + row * 68 + e * 8;
            f32x4 x0 = *reinterpret_cast<const f32x4*>(sp);
            f32x4 x1 = *reinterpret_cast<const f32x4*>(sp + 4);
            float mt = fmaxf(fmaxf(fmaxf(x0[0], x0[1]), fmaxf(x0[2], x0[3])),
                             fmaxf(fmaxf(x1[0], x1[1]), fmaxf(x1[2], x1[3])));
            #pragma unroll
            for (int m = 1; m <= 4; m <<= 1) mt = fmaxf(mt, __shfl_xor(mt, m, 64));
            float m_old = stm[row];
            float m_new = (mt > m_old + 8.0f) ? mt : m_old;    // defer-max THR=8
            float e0 = __expf(x0[0] - m_new), e1 = __expf(x0[1] - m_new);
            float e2 = __expf(x0[2] - m_new), e3 = __expf(x0[3] - m_new);
            float e4 = __expf(x1[0] - m_new), e5 = __expf(x1[1] - m_new);
            float e6 = __expf(x1[2] - m_new), e7 = __expf(x1[3] - m_new);
            float lt = ((e0 + e1) + (e2 + e3)) + ((e4 + e5) + (e6 + e7));
            #pragma unroll
            for (int m = 1; m <= 4; m <<= 1) lt += __shfl_xor(lt, m, 64);
            u32x4 pk;
            pk[0] = (unsigned)f2bf(e0) | ((unsigned)f2bf(e1) << 16);
            pk[1] = (unsigned)f2bf(e2) | ((unsigned)f2bf(e3) << 16);
            pk[2] = (unsigned)f2bf(e4) | ((unsigned)f2bf(e5) << 16);
            pk[3] = (unsigned)f2bf(e6) | ((unsigned)f2bf(e7) << 16);
            *reinterpret_cast<u32x4*>(Pb + row * 72 + e * 8) = pk;
            if (e == 0) {
                float alpha = (m_new == m_old) ? 1.0f : __expf(m_old - m_new);
                sts[row] = alpha;
                stm[row] = m_new;
                stl[row] = stl[row] * alpha + lt;
            }
        }
        waitlg0();
        __builtin_amdgcn_s_barrier();

        // ---- phase C: retire V(kt); rescale O + PV(kt); load K(kt+2) ----
        WAITV(0);
        {
            f32x4 al[4];
            bool need = false;
            #pragma unroll
            for (int c = 0; c < 4; ++c) {
                al[c] = *reinterpret_cast<const f32x4*>(sts + qi2 * 32 + 4 * lh1 + 8 * c);
                #pragma unroll
                for (int j = 0; j < 4; ++j) need = need || (al[c][j] != 1.0f);
            }
            if (__any((int)need)) {
                #pragma unroll
                for (int td = 0; td < 4; ++td)
                    #pragma unroll
                    for (int rr = 0; rr < 16; ++rr)
                        o[td][rr] *= al[rr >> 2][rr & 3];
            }
            bf16x8 paf[4];
            const unsigned short* prow = Pb + (qi2 * 32 + l31) * 72 + lh1 * 8;
            #pragma unroll
            for (int w16 = 0; w16 < 4; ++w16) paf[w16] = ld_bf8(prow + w16 * 16);
            __builtin_amdgcn_s_setprio(1);
            #pragma unroll
            for (int w16 = 0; w16 < 4; ++w16) {
                #pragma unroll
                for (int td = 0; td < 4; ++td) {
                    int d = dq * 128 + td * 32 + l31;
                    bf16x8 vf = ld_bf8(Vt + d * 64 + (((w16 * 2 + lh1) ^ (d & 7)) * 8));
                    o[td] = mfma32(paf[w16], vf, o[td]);
                }
            }
            __builtin_amdgcn_s_setprio(0);
        }
        waitlg0();
        {
            int nk = kt + 2 < NT ? kt + 2 : NT - 1;   // clamp: uniform vmcnt counts
            loadK(nk);
        }
        __builtin_amdgcn_s_barrier();
    }

    // ---- epilogue ----
    {
        f32x4 li[4];
        #pragma unroll
        for (int c = 0; c < 4; ++c) {
            f32x4 lv = *reinterpret_cast<const f32x4*>(stl + qi2 * 32 + 4 * lh1 + 8 * c);
            #pragma unroll
            for (int j = 0; j < 4; ++j) li[c][j] = 1.0f / lv[j];
        }
        #pragma unroll
        for (int td = 0; td < 4; ++td) {
            int col = dq * 128 + td * 32 + l31;
            #pragma unroll
            for (int rr = 0; rr < 16; ++rr) {
                int cr  = (rr & 3) + 8 * (rr >> 2) + 4 * lh1;
                int row = qb + qi2 * 32 + cr;
                out[(size_t)row * (BATCH * DIM) + (size_t)b * DIM + col] =
                    o[td][rr] * li[rr >> 2][rr & 3];
            }
        }
    }
}

extern "C" void kernel_launch(void* const* d_in, const int* in_sizes, int n_in,
                              void* d_out, int out_size, void* d_ws, size_t ws_size,
                              hipStream_t stream) {
    const float* seq = (const float*)d_in[0];   // [S][B][D] f32
    const float* wv  = (const float*)d_in[1];   // [D][D] f32
    const float* bv  = (const float*)d_in[2];   // [D] f32
    float* outp = (float*)d_out;                // [S][B][D] f32

    unsigned short* wsVal = (unsigned short*)d_ws;                          // 32 MB
    unsigned short* wsVt  = (unsigned short*)((char*)d_ws + 33554432);      // 32 MB

    pack_vt<<<dim3(S_LEN / 32, DIM / 32, BATCH), dim3(256), 0, stream>>>(seq, wsVt);
    gemm_value<<<dim3(BATCH * S_LEN / 64, DIM / 64), dim3(256), 0, stream>>>(
        seq, wv, bv, wsVal);
    attn_fused<<<dim3(512), dim3(512), 158464, stream>>>(wsVal, wsVt, outp);
}